// Round 2
// baseline (266.256 us; speedup 1.0000x reference)
//
#include <hip/hip_runtime.h>

#define SS 128
#define RR 128
#define CC 128
#define SCH 8          // s-slabs marched per block; U boundary redundancy = 1/SCH
#define EPSF 1e-14f

constexpr int SRC = SS * RR * CC;
constexpr int RC  = RR * CC;

// One slab's full work for one thread (4 voxels): CO term, c-diff, r-diff,
// and (if SDIFF) s-diff against prev[] held in registers. Updates prev.
template <bool SDIFF>
__device__ __forceinline__ void slab(const float* __restrict__ Up,
                                     const float* __restrict__ Lp,
                                     int offr, float wr, float wc,
                                     float4 (&prev)[9],
                                     float& a_dc, float& a_dr,
                                     float& a_ds, float& a_co) {
    float4 l0 = *(const float4*)(Lp);
    float4 l1 = *(const float4*)(Lp + SRC);
    float4 l2 = *(const float4*)(Lp + 2 * SRC);
    float L0v[4] = {l0.x, l0.y, l0.z, l0.w};
    float L1v[4] = {l1.x, l1.y, l1.z, l1.w};
    float L2v[4] = {l2.x, l2.y, l2.z, l2.w};
    int idx[4];
#pragma unroll
    for (int j = 0; j < 4; ++j) {
        int id = 0;
        float best = L0v[j];
        if (L1v[j] > best) { best = L1v[j]; id = 1; }
        if (L2v[j] > best) { best = L2v[j]; id = 2; }
        idx[j] = id;
    }

    float am[3][4];
#pragma unroll
    for (int g = 0; g < 3; ++g)
#pragma unroll
        for (int j = 0; j < 4; ++j) am[g][j] = 0.f;

    float t_dcb = 0.f, t_dr = 0.f;

#pragma unroll
    for (int ch = 0; ch < 9; ++ch) {
        float4 uu = *(const float4*)(Up + ch * SRC);
        float4 vr = *(const float4*)(Up + ch * SRC + offr);

        int g = ch / 3, m = ch % 3;
        float uuv[4] = {uu.x, uu.y, uu.z, uu.w};
#pragma unroll
        for (int j = 0; j < 4; ++j)
            if (idx[j] == m) am[g][j] = fabsf(uuv[j]);

        float d;
        // c-diffs (3 internal + 1 boundary via shfl; lanes 31/63 masked by wc)
        d = uu.y - uu.x; a_dc += d * d;
        d = uu.z - uu.y; a_dc += d * d;
        d = uu.w - uu.z; a_dc += d * d;
        float un = __shfl_down(uu.x, 1);
        d = un - uu.w; t_dcb += d * d;

        // r-diff (row+1: same-block L1/L2 hit for rows 0..6)
        d = vr.x - uu.x; t_dr += d * d;
        d = vr.y - uu.y; t_dr += d * d;
        d = vr.z - uu.z; t_dr += d * d;
        d = vr.w - uu.w; t_dr += d * d;

        if (SDIFF) {
            float4 pv = prev[ch];
            d = uu.x - pv.x; a_ds += d * d;
            d = uu.y - pv.y; a_ds += d * d;
            d = uu.z - pv.z; a_ds += d * d;
            d = uu.w - pv.w; a_ds += d * d;
        }
        prev[ch] = uu;
    }
    a_dc += wc * t_dcb;
    a_dr += wr * t_dr;

#pragma unroll
    for (int j = 0; j < 4; ++j) {
        float e1 = am[0][j], e2 = am[1][j], e3 = am[2][j];
        float den = fmaxf(e1 * e1 + e2 * e2 + e3 * e3, EPSF);
        float num = 0.5f * ((e1 - e2) * (e1 - e2) + (e2 - e3) * (e2 - e3) +
                            (e3 - e1) * (e3 - e1));
        a_co += sqrtf(num / den);
    }
}

// Block = 256 threads = 8 rows x 32 float4-cols, marching SCH=8 s-slabs.
// ss=0 is peeled (slab<false>): no preload, no zero s-diff -> compulsory-only.
// launch_bounds(256,2): 2 blocks/CU co-resident (512-block grid), 256-VGPR cap
// so the compiler can batch a full slab's 21 loads per wave (deep MLP).
__global__ __launch_bounds__(256, 2) void scol_main(const float* __restrict__ L,
                                                    const float* __restrict__ U,
                                                    float4* __restrict__ part) {
    // bijective XCD swizzle: grid = 512 (divisible by 8). Consecutive logical
    // blocks (rt fastest, then sc) share an XCD -> r-tile and s-chunk boundary
    // re-reads hit that XCD's L2.
    int bid = blockIdx.x;
    int cpx = gridDim.x >> 3;
    int swz = (bid & 7) * cpx + (bid >> 3);

    int rt = swz & 15;           // r-tile: 16 tiles of 8 rows
    int sc = (swz >> 4) & 15;    // s-chunk: 16 chunks of SCH=8
    int b  = swz >> 8;           // batch

    int tid = threadIdx.x;
    int c4       = tid & 31;
    int rowLocal = tid >> 5;     // 0..7
    int r  = (rt << 3) + rowLocal;
    int s0 = sc * SCH;
    int c  = c4 << 2;

    bool hr = (r < RR - 1), hc = (c4 < 31);
    float wr = hr ? 1.f : 0.f;
    float wc = hc ? 1.f : 0.f;
    int offr = hr ? CC : 0;      // clamped: boundary re-loads self, weight 0

    int pos = (s0 * RR + r) * CC + c;
    const float* Ub = U + (size_t)b * 9 * SRC + pos;
    const float* Lb = L + (size_t)b * 3 * SRC + pos;

    float a_dc = 0.f, a_dr = 0.f, a_ds = 0.f, a_co = 0.f;
    float4 prev[9];

    // peeled first slab: fills prev, no s-diff, no redundant re-read
    slab<false>(Ub, Lb, offr, wr, wc, prev, a_dc, a_dr, a_ds, a_co);

#pragma unroll 1
    for (int ss = 1; ss < SCH; ++ss)
        slab<true>(Ub + ss * RC, Lb + ss * RC, offr, wr, wc, prev,
                   a_dc, a_dr, a_ds, a_co);

    // chunk-boundary s-diff: next chunk's first slab (same-XCD L2 hit against
    // the co-resident neighbor block) vs prev = slab s0+SCH-1.
    if (s0 + SCH < SS) {
        const float* Up = Ub + SCH * RC;
#pragma unroll
        for (int ch = 0; ch < 9; ++ch) {
            float4 uu = *(const float4*)(Up + ch * SRC);
            float4 pv = prev[ch];
            float d;
            d = uu.x - pv.x; a_ds += d * d;
            d = uu.y - pv.y; a_ds += d * d;
            d = uu.z - pv.z; a_ds += d * d;
            d = uu.w - pv.w; a_ds += d * d;
        }
    }

    // ---------- wave reduce (64 lanes) ----------
#pragma unroll
    for (int off = 32; off > 0; off >>= 1) {
        a_co += __shfl_down(a_co, off);
        a_ds += __shfl_down(a_ds, off);
        a_dr += __shfl_down(a_dr, off);
        a_dc += __shfl_down(a_dc, off);
    }

    __shared__ float s_co[4], s_ds[4], s_dr[4], s_dc[4];
    int wid  = threadIdx.x >> 6;
    int lane = threadIdx.x & 63;
    if (lane == 0) {
        s_co[wid] = a_co; s_ds[wid] = a_ds;
        s_dr[wid] = a_dr; s_dc[wid] = a_dc;
    }
    __syncthreads();
    if (threadIdx.x == 0) {
        float t_co = 0.f, t_s = 0.f, t_r = 0.f, t_c = 0.f;
        for (int w = 0; w < 4; ++w) {
            t_co += s_co[w]; t_s += s_ds[w];
            t_r += s_dr[w]; t_c += s_dc[w];
        }
        part[blockIdx.x] = make_float4(t_co, t_s, t_r, t_c);
    }
}

// Single block: reduce nblk float4 partials in double, emit the scalar.
__global__ __launch_bounds__(256) void scol_final(const float4* __restrict__ part,
                                                  float* __restrict__ out,
                                                  int nblk, int B) {
    double d_co = 0., d_ds = 0., d_dr = 0., d_dc = 0.;
    for (int i = threadIdx.x; i < nblk; i += blockDim.x) {
        float4 p = part[i];
        d_co += (double)p.x; d_ds += (double)p.y;
        d_dr += (double)p.z; d_dc += (double)p.w;
    }
#pragma unroll
    for (int off = 32; off > 0; off >>= 1) {
        d_co += __shfl_down(d_co, off);
        d_ds += __shfl_down(d_ds, off);
        d_dr += __shfl_down(d_dr, off);
        d_dc += __shfl_down(d_dc, off);
    }
    __shared__ double sh[4][4];
    int wid  = threadIdx.x >> 6;
    int lane = threadIdx.x & 63;
    if (lane == 0) {
        sh[wid][0] = d_co; sh[wid][1] = d_ds;
        sh[wid][2] = d_dr; sh[wid][3] = d_dc;
    }
    __syncthreads();
    if (threadIdx.x == 0) {
        double t_co = 0., t_ds = 0., t_dr = 0., t_dc = 0.;
        for (int w = 0; w < 4; ++w) {
            t_co += sh[w][0]; t_ds += sh[w][1];
            t_dr += sh[w][2]; t_dc += sh[w][3];
        }
        double nvox = (double)B * SS * RR * CC;
        double nds  = (double)B * (SS - 1) * RR * CC;
        double ndr  = (double)B * SS * (RR - 1) * CC;
        double ndc  = (double)B * SS * RR * (CC - 1);
        out[0] = (float)(0.5 * (t_co / nvox + t_ds / nds + t_dr / ndr + t_dc / ndc));
    }
}

extern "C" void kernel_launch(void* const* d_in, const int* in_sizes, int n_in,
                              void* d_out, int out_size, void* d_ws, size_t ws_size,
                              hipStream_t stream) {
    const float* L = (const float*)d_in[0];
    const float* U = (const float*)d_in[1];
    float* out = (float*)d_out;

    int B = in_sizes[1] / (9 * SS * RR * CC);
    int blocks = B * (SS / SCH) * (RR / 8);   // 512 for B=2, 2 blocks/CU

    float4* part = (float4*)d_ws;

    hipLaunchKernelGGL(scol_main, dim3(blocks), dim3(256), 0, stream,
                       L, U, part);
    hipLaunchKernelGGL(scol_final, dim3(1), dim3(256), 0, stream,
                       part, out, blocks, B);
}

// Round 3
// 249.796 us; speedup vs baseline: 1.0659x; 1.0659x over previous
//
#include <hip/hip_runtime.h>

#define SS 128
#define RR 128
#define CC 128
#define SCH 4          // s-slabs marched per block; peeled -> U redundancy 1/SCH
#define EPSF 1e-14f

constexpr int SRC = SS * RR * CC;
constexpr int RC  = RR * CC;

// 9 far loads for one slab's U channels into a named register buffer.
__device__ __forceinline__ void load_u(const float* __restrict__ Up,
                                       float4 (&buf)[9]) {
#pragma unroll
    for (int ch = 0; ch < 9; ++ch)
        buf[ch] = *(const float4*)(Up + ch * SRC);
}

// s-diff between two register-resident slabs.
__device__ __forceinline__ void sdiff9(const float4 (&cur)[9],
                                       const float4 (&prv)[9], float& a_ds) {
#pragma unroll
    for (int ch = 0; ch < 9; ++ch) {
        float d;
        d = cur[ch].x - prv[ch].x; a_ds += d * d;
        d = cur[ch].y - prv[ch].y; a_ds += d * d;
        d = cur[ch].z - prv[ch].z; a_ds += d * d;
        d = cur[ch].w - prv[ch].w; a_ds += d * d;
    }
}

// CO + c-diff + r-diff for one slab whose U is already in registers.
// vr (row+1) loads are same-block L1/L2 hits; L loads are compulsory.
__device__ __forceinline__ void compute_slab(const float4 (&u)[9],
                                             const float* __restrict__ Up,
                                             const float* __restrict__ Lp,
                                             int offr, float wr, float wc,
                                             float& a_dc, float& a_dr,
                                             float& a_co) {
    float4 l0 = *(const float4*)(Lp);
    float4 l1 = *(const float4*)(Lp + SRC);
    float4 l2 = *(const float4*)(Lp + 2 * SRC);
    float L0v[4] = {l0.x, l0.y, l0.z, l0.w};
    float L1v[4] = {l1.x, l1.y, l1.z, l1.w};
    float L2v[4] = {l2.x, l2.y, l2.z, l2.w};
    int idx[4];
#pragma unroll
    for (int j = 0; j < 4; ++j) {
        int id = 0;
        float best = L0v[j];
        if (L1v[j] > best) { best = L1v[j]; id = 1; }
        if (L2v[j] > best) { best = L2v[j]; id = 2; }
        idx[j] = id;
    }

    float am[3][4];
#pragma unroll
    for (int g = 0; g < 3; ++g)
#pragma unroll
        for (int j = 0; j < 4; ++j) am[g][j] = 0.f;

    float t_dcb = 0.f, t_dr = 0.f;

#pragma unroll
    for (int ch = 0; ch < 9; ++ch) {
        float4 uu = u[ch];
        float4 vr = *(const float4*)(Up + ch * SRC + offr);

        int g = ch / 3, m = ch % 3;
        float uuv[4] = {uu.x, uu.y, uu.z, uu.w};
#pragma unroll
        for (int j = 0; j < 4; ++j)
            if (idx[j] == m) am[g][j] = fabsf(uuv[j]);

        float d;
        d = uu.y - uu.x; a_dc += d * d;
        d = uu.z - uu.y; a_dc += d * d;
        d = uu.w - uu.z; a_dc += d * d;
        float un = __shfl_down(uu.x, 1);      // lanes 31/63 masked by wc
        d = un - uu.w; t_dcb += d * d;

        d = vr.x - uu.x; t_dr += d * d;
        d = vr.y - uu.y; t_dr += d * d;
        d = vr.z - uu.z; t_dr += d * d;
        d = vr.w - uu.w; t_dr += d * d;
    }
    a_dc += wc * t_dcb;
    a_dr += wr * t_dr;

#pragma unroll
    for (int j = 0; j < 4; ++j) {
        float e1 = am[0][j], e2 = am[1][j], e3 = am[2][j];
        float den = fmaxf(e1 * e1 + e2 * e2 + e3 * e3, EPSF);
        float num = 0.5f * ((e1 - e2) * (e1 - e2) + (e2 - e3) * (e2 - e3) +
                            (e3 - e1) * (e3 - e1));
        a_co += sqrtf(num / den);
    }
}

// Block = 256 threads = 8 rows x 32 float4-cols, marching SCH=4 s-slabs with
// an explicit A/B register double-buffer: slab ss+1's far loads are issued
// before slab ss's compute; the s-diff consumes the old buffer as soon as its
// loads land, freeing it for the next prefetch. Fully hand-unrolled so all
// buffer indices are static (no scratch). 1024 blocks = 4 blocks/CU exactly.
__global__ __launch_bounds__(256, 4) void scol_main(const float* __restrict__ L,
                                                    const float* __restrict__ U,
                                                    float4* __restrict__ part) {
    // bijective XCD swizzle (grid 1024, divisible by 8): consecutive logical
    // blocks (rt fastest, then sc) share an XCD L2.
    int bid = blockIdx.x;
    int cpx = gridDim.x >> 3;
    int swz = (bid & 7) * cpx + (bid >> 3);

    int rt = swz & 15;            // r-tile: 16 tiles of 8 rows
    int sc = (swz >> 4) & 31;     // s-chunk: 32 chunks of SCH=4
    int b  = swz >> 9;            // batch

    int tid = threadIdx.x;
    int c4       = tid & 31;
    int rowLocal = tid >> 5;      // 0..7
    int r  = (rt << 3) + rowLocal;
    int s0 = sc * SCH;
    int c  = c4 << 2;

    bool hr = (r < RR - 1), hc = (c4 < 31);
    float wr = hr ? 1.f : 0.f;
    float wc = hc ? 1.f : 0.f;
    int offr = hr ? CC : 0;       // clamped: boundary re-loads self, weight 0
    // chunk-boundary slab: clamped to self -> sdiff contributes exactly 0
    int offb = (s0 + SCH < SS) ? SCH * RC : (SCH - 1) * RC;

    int pos = (s0 * RR + r) * CC + c;
    const float* Ub = U + (size_t)b * 9 * SRC + pos;
    const float* Lb = L + (size_t)b * 3 * SRC + pos;

    float a_dc = 0.f, a_dr = 0.f, a_ds = 0.f, a_co = 0.f;

    float4 A[9], B[9];

    // ---- software-pipelined 4-slab chain ----
    load_u(Ub, A);                                    // slab 0
    load_u(Ub + RC, B);                               // prefetch slab 1
    compute_slab(A, Ub, Lb, offr, wr, wc, a_dc, a_dr, a_co);

    sdiff9(B, A, a_ds);                               // slab1 - slab0; A free
    load_u(Ub + 2 * RC, A);                           // prefetch slab 2
    compute_slab(B, Ub + RC, Lb + RC, offr, wr, wc, a_dc, a_dr, a_co);

    sdiff9(A, B, a_ds);                               // slab2 - slab1; B free
    load_u(Ub + 3 * RC, B);                           // prefetch slab 3
    compute_slab(A, Ub + 2 * RC, Lb + 2 * RC, offr, wr, wc, a_dc, a_dr, a_co);

    sdiff9(B, A, a_ds);                               // slab3 - slab2; A free
    load_u(Ub + offb, A);                             // prefetch boundary slab
    compute_slab(B, Ub + 3 * RC, Lb + 3 * RC, offr, wr, wc, a_dc, a_dr, a_co);

    sdiff9(A, B, a_ds);                               // boundary (0 if clamped)

    // ---------- wave reduce (64 lanes) ----------
#pragma unroll
    for (int off = 32; off > 0; off >>= 1) {
        a_co += __shfl_down(a_co, off);
        a_ds += __shfl_down(a_ds, off);
        a_dr += __shfl_down(a_dr, off);
        a_dc += __shfl_down(a_dc, off);
    }

    __shared__ float s_co[4], s_ds[4], s_dr[4], s_dc[4];
    int wid  = threadIdx.x >> 6;
    int lane = threadIdx.x & 63;
    if (lane == 0) {
        s_co[wid] = a_co; s_ds[wid] = a_ds;
        s_dr[wid] = a_dr; s_dc[wid] = a_dc;
    }
    __syncthreads();
    if (threadIdx.x == 0) {
        float t_co = 0.f, t_s = 0.f, t_r = 0.f, t_c = 0.f;
        for (int w = 0; w < 4; ++w) {
            t_co += s_co[w]; t_s += s_ds[w];
            t_r += s_dr[w]; t_c += s_dc[w];
        }
        part[blockIdx.x] = make_float4(t_co, t_s, t_r, t_c);
    }
}

// Single block: reduce nblk float4 partials in double, emit the scalar.
__global__ __launch_bounds__(256) void scol_final(const float4* __restrict__ part,
                                                  float* __restrict__ out,
                                                  int nblk, int B) {
    double d_co = 0., d_ds = 0., d_dr = 0., d_dc = 0.;
    for (int i = threadIdx.x; i < nblk; i += blockDim.x) {
        float4 p = part[i];
        d_co += (double)p.x; d_ds += (double)p.y;
        d_dr += (double)p.z; d_dc += (double)p.w;
    }
#pragma unroll
    for (int off = 32; off > 0; off >>= 1) {
        d_co += __shfl_down(d_co, off);
        d_ds += __shfl_down(d_ds, off);
        d_dr += __shfl_down(d_dr, off);
        d_dc += __shfl_down(d_dc, off);
    }
    __shared__ double sh[4][4];
    int wid  = threadIdx.x >> 6;
    int lane = threadIdx.x & 63;
    if (lane == 0) {
        sh[wid][0] = d_co; sh[wid][1] = d_ds;
        sh[wid][2] = d_dr; sh[wid][3] = d_dc;
    }
    __syncthreads();
    if (threadIdx.x == 0) {
        double t_co = 0., t_ds = 0., t_dr = 0., t_dc = 0.;
        for (int w = 0; w < 4; ++w) {
            t_co += sh[w][0]; t_ds += sh[w][1];
            t_dr += sh[w][2]; t_dc += sh[w][3];
        }
        double nvox = (double)B * SS * RR * CC;
        double nds  = (double)B * (SS - 1) * RR * CC;
        double ndr  = (double)B * SS * (RR - 1) * CC;
        double ndc  = (double)B * SS * RR * (CC - 1);
        out[0] = (float)(0.5 * (t_co / nvox + t_ds / nds + t_dr / ndr + t_dc / ndc));
    }
}

extern "C" void kernel_launch(void* const* d_in, const int* in_sizes, int n_in,
                              void* d_out, int out_size, void* d_ws, size_t ws_size,
                              hipStream_t stream) {
    const float* L = (const float*)d_in[0];
    const float* U = (const float*)d_in[1];
    float* out = (float*)d_out;

    int B = in_sizes[1] / (9 * SS * RR * CC);
    int blocks = B * (SS / SCH) * (RR / 8);   // 1024 for B=2: 4 blocks/CU exact

    float4* part = (float4*)d_ws;

    hipLaunchKernelGGL(scol_main, dim3(blocks), dim3(256), 0, stream,
                       L, U, part);
    hipLaunchKernelGGL(scol_final, dim3(1), dim3(256), 0, stream,
                       part, out, blocks, B);
}